// Round 1
// baseline (26.751 us; speedup 1.0000x reference)
//
#include <hip/hip_runtime.h>

// ATSS-style 1D regression loss (RegressionLoss_65936337928514).
//
// Structure (from reference):
//   B=4 images, M=64 gts/image, A=190464 anchors in 5 levels.
//   Per level: locations with stride 8*2^l, 3 anchors per location
//   (same center, widths 16*2^l * 2^{0,1/3,2/3}).
//   Per (image, gt): top-27 nearest anchors per level by |cx-gcx|
//   = contiguous window of 9 locations x 3 anchors (centers are an
//   arithmetic progression; distance is V-shaped in location index).
//   K = 135 candidates; thresh = mean + unbiased std of candidate IoU;
//   positive if iou >= thresh and center strictly inside gt (margin .01).
//   Per anchor: best gt = argmax iou over gts where anchor is positive
//   (first index on ties). Smooth-L1 (beta=1/3) on (dx, dw) targets,
//   mean over 2*num_pos.

static constexpr int NLEV = 5;
static constexpr int B_IMG = 4;
static constexpr int M_GT = 64;
static constexpr int A_TOTAL = 190464;
static constexpr int K_CAND = 135;  // 27 * 5

__device__ __constant__ int d_LOCS[NLEV]   = {32768, 16384, 8192, 4096, 2048};
__device__ __constant__ int d_ASTART[NLEV] = {0, 98304, 147456, 172032, 184320};

// ---------------------------------------------------------------------------
// Kernel 1: one wave (64 threads) per (image, gt). Finds the 135 candidates,
// computes mean/std threshold, and atomicMax-packs positive (iou, m) per anchor.
// Pack: high 32 = float bits of iou (iou > 0 so order-preserving as uint),
// low 32 = ~m (so equal iou -> smaller m wins, matching argmax-first).
// Sentinel 0 = "no positive candidate" (any positive has iou > 0).
// ---------------------------------------------------------------------------
__global__ __launch_bounds__(64) void atss_assign(
    const float* __restrict__ anchors,      // [A,2]
    const float* __restrict__ ann,          // [B,M,3]
    unsigned long long* __restrict__ packed /* [B*A] zero-initialized */)
{
    const int bm = blockIdx.x;
    const int b = bm >> 6;   // M_GT == 64
    const int m = bm & 63;
    const int lane = threadIdx.x;

    const float g0 = ann[(b * M_GT + m) * 3 + 0];
    const float g1 = ann[(b * M_GT + m) * 3 + 1];
    const float gcx = (g0 + g1) * 0.5f;

    // --- per-level window of 9 locations (computed redundantly per lane;
    //     all loads are wave-uniform broadcasts) ---
    int winStart[NLEV];
#pragma unroll
    for (int lvl = 0; lvl < NLEV; ++lvl) {
        const int locs = d_LOCS[lvl];
        const int base = d_ASTART[lvl];
        const float stride = (float)(8 << lvl);

        auto cxof = [&](int t) -> float {
            const int a = base + 3 * t;
            return (anchors[2 * a] + anchors[2 * a + 1]) * 0.5f;
        };

        int j = (int)(gcx / stride);
        if (j < 0) j = 0;
        if (j > locs - 1) j = locs - 1;

        // nearest location, tie -> lower index (strict < keeps first)
        int bi = j;
        float bd = INFINITY;
        for (int t = j - 1; t <= j + 1; ++t) {
            if (t < 0 || t >= locs) continue;
            const float d = fabsf(cxof(t) - gcx);
            if (d < bd) { bd = d; bi = t; }
        }

        // two-pointer expansion to 9 locations; tie -> left (lower index),
        // matching jax.lax.top_k's stable lower-index-first tie-breaking.
        int lo = bi, hi = bi;
#pragma unroll
        for (int s = 0; s < 8; ++s) {
            const float dl = (lo - 1 >= 0)   ? fabsf(cxof(lo - 1) - gcx) : INFINITY;
            const float dr = (hi + 1 < locs) ? fabsf(cxof(hi + 1) - gcx) : INFINITY;
            if (dl <= dr) --lo; else ++hi;
        }
        winStart[lvl] = lo;
    }

    // --- candidates: lane handles k = lane, lane+64, lane+128 ---
    float ci[3];
    int   ca[3];
    bool  cok[3];
#pragma unroll
    for (int i = 0; i < 3; ++i) {
        const int k = lane + 64 * i;
        ci[i] = 0.0f; ca[i] = -1; cok[i] = false;
        if (k < K_CAND) {
            const int lvl = k / 27;
            const int r = k % 27;
            const int loc = winStart[lvl] + r / 3;
            const int a = d_ASTART[lvl] + loc * 3 + (r % 3);
            const float a0 = anchors[2 * a];
            const float a1 = anchors[2 * a + 1];
            float inter = fminf(a1, g1) - fmaxf(a0, g0);
            inter = fmaxf(inter, 0.0f);
            const float uni = (a1 - a0) + (g1 - g0) - inter;
            const float iou = inter / fmaxf(uni, 1e-8f);
            const float cx = (a0 + a1) * 0.5f;
            ci[i] = iou;
            ca[i] = a;
            cok[i] = fminf(cx - g0, g1 - cx) > 0.01f;
        }
    }

    // --- mean / unbiased std over the 135 candidates (wave butterfly) ---
    float s = ci[0] + ci[1] + ci[2];  // invalid slots contribute 0
#pragma unroll
    for (int off = 32; off >= 1; off >>= 1) s += __shfl_xor(s, off);
    const float mean = s / 135.0f;

    float s2 = 0.0f;
#pragma unroll
    for (int i = 0; i < 3; ++i) {
        if (ca[i] >= 0) { const float d = ci[i] - mean; s2 += d * d; }
    }
#pragma unroll
    for (int off = 32; off >= 1; off >>= 1) s2 += __shfl_xor(s2, off);
    const float thresh = mean + sqrtf(s2 / 134.0f);

    // --- scatter positives ---
    unsigned long long* pb = packed + (size_t)b * A_TOTAL;
#pragma unroll
    for (int i = 0; i < 3; ++i) {
        if (ca[i] >= 0 && cok[i] && ci[i] >= thresh) {
            const unsigned int bits = __float_as_uint(ci[i]);
            const unsigned long long p =
                ((unsigned long long)bits << 32) | (unsigned int)(~m);
            atomicMax(pb + ca[i], p);
        }
    }
}

// ---------------------------------------------------------------------------
// Kernel 2: per-anchor smooth-L1 for positive anchors; deterministic
// per-block partial sums (no float atomics).
// ---------------------------------------------------------------------------
__global__ __launch_bounds__(256) void atss_loss(
    const float* __restrict__ reg,          // [B,A,2]
    const float* __restrict__ anchors,      // [A,2]
    const float* __restrict__ ann,          // [B,M,3]
    const unsigned long long* __restrict__ packed,
    float* __restrict__ partial_loss,       // [B * gridDim.x]
    unsigned int* __restrict__ partial_cnt) // [B * gridDim.x]
{
    const int b = blockIdx.y;
    const int a = blockIdx.x * 256 + threadIdx.x;

    float loss = 0.0f;
    unsigned int cnt = 0;
    if (a < A_TOTAL) {
        const unsigned long long p = packed[(size_t)b * A_TOTAL + a];
        if (p != 0ULL) {
            const int m = (int)(~(unsigned int)(p & 0xFFFFFFFFULL));
            const float g0 = ann[(b * M_GT + m) * 3 + 0];
            const float g1 = ann[(b * M_GT + m) * 3 + 1];
            const float a0 = anchors[2 * a];
            const float a1 = anchors[2 * a + 1];
            const float aw = a1 - a0;
            const float ac = a0 + 0.5f * aw;
            const float gwr = g1 - g0;
            const float gc = g0 + 0.5f * gwr;
            const float gw = fmaxf(gwr, 1.0f);
            const float dx = (gc - ac) / aw / 0.1f;
            const float dw = logf(gw / aw) / 0.2f;
            const float* r = reg + ((size_t)b * A_TOTAL + a) * 2;
            const float d0 = fabsf(dx - r[0]);
            const float d1 = fabsf(dw - r[1]);
            const float beta = 1.0f / 3.0f;
            const float l0 = (d0 <= beta) ? 0.5f * 3.0f * d0 * d0 : d0 - 0.5f / 3.0f;
            const float l1 = (d1 <= beta) ? 0.5f * 3.0f * d1 * d1 : d1 - 0.5f / 3.0f;
            loss = l0 + l1;
            cnt = 1;
        }
    }

    __shared__ float sl[256];
    __shared__ unsigned int sc[256];
    sl[threadIdx.x] = loss;
    sc[threadIdx.x] = cnt;
    __syncthreads();
    for (int off = 128; off >= 1; off >>= 1) {
        if (threadIdx.x < off) {
            sl[threadIdx.x] += sl[threadIdx.x + off];
            sc[threadIdx.x] += sc[threadIdx.x + off];
        }
        __syncthreads();
    }
    if (threadIdx.x == 0) {
        partial_loss[b * gridDim.x + blockIdx.x] = sl[0];
        partial_cnt[b * gridDim.x + blockIdx.x] = sc[0];
    }
}

// ---------------------------------------------------------------------------
// Kernel 3: per-image final reduce + normalize. Deterministic.
// ---------------------------------------------------------------------------
__global__ __launch_bounds__(256) void atss_final(
    const float* __restrict__ partial_loss,
    const unsigned int* __restrict__ partial_cnt,
    int nblocks,
    float* __restrict__ out)
{
    const int b = blockIdx.x;
    __shared__ float sl[256];
    __shared__ unsigned int sc[256];
    float s = 0.0f;
    unsigned int c = 0;
    for (int i = threadIdx.x; i < nblocks; i += 256) {
        s += partial_loss[b * nblocks + i];
        c += partial_cnt[b * nblocks + i];
    }
    sl[threadIdx.x] = s;
    sc[threadIdx.x] = c;
    __syncthreads();
    for (int off = 128; off >= 1; off >>= 1) {
        if (threadIdx.x < off) {
            sl[threadIdx.x] += sl[threadIdx.x + off];
            sc[threadIdx.x] += sc[threadIdx.x + off];
        }
        __syncthreads();
    }
    if (threadIdx.x == 0) {
        const unsigned int np = sc[0];
        const unsigned int denom_i = (2u * np > 1u) ? 2u * np : 1u;
        out[b] = (np > 0) ? sl[0] / (float)denom_i : 0.0f;
    }
}

extern "C" void kernel_launch(void* const* d_in, const int* in_sizes, int n_in,
                              void* d_out, int out_size, void* d_ws, size_t ws_size,
                              hipStream_t stream) {
    const float* reg     = (const float*)d_in[0];  // [B,A,2]
    const float* anchors = (const float*)d_in[1];  // [A,2]
    const float* ann     = (const float*)d_in[2];  // [B,M,3]
    // d_in[3] = class_id (unused: reference keeps all rows)
    float* out = (float*)d_out;                    // [B]

    const size_t packed_bytes = (size_t)B_IMG * A_TOTAL * sizeof(unsigned long long);
    const int nblk = (A_TOTAL + 255) / 256;  // 744

    unsigned long long* packed = (unsigned long long*)d_ws;
    float* partial_loss = (float*)((char*)d_ws + packed_bytes);
    unsigned int* partial_cnt =
        (unsigned int*)((char*)d_ws + packed_bytes + (size_t)B_IMG * nblk * sizeof(float));

    // zero the packed buffer each call (harness poisons ws once; we must init)
    hipMemsetAsync(d_ws, 0, packed_bytes, stream);

    atss_assign<<<B_IMG * M_GT, 64, 0, stream>>>(anchors, ann, packed);
    atss_loss<<<dim3(nblk, B_IMG), 256, 0, stream>>>(reg, anchors, ann, packed,
                                                     partial_loss, partial_cnt);
    atss_final<<<B_IMG, 256, 0, stream>>>(partial_loss, partial_cnt, nblk, out);
}